// Round 7
// baseline (232.174 us; speedup 1.0000x reference)
//
#include <hip/hip_runtime.h>

#define B_ 2
#define S_ 2048
#define D_ 1024
#define H_ 16

typedef unsigned short u16;
typedef __bf16 bf16x8 __attribute__((ext_vector_type(8)));
typedef float f32x4 __attribute__((ext_vector_type(4)));
typedef unsigned short u16x8 __attribute__((ext_vector_type(8)));

__device__ __forceinline__ unsigned swz(unsigned o) {
  // XOR bits 4-6 with row low bits; row stride is 128B for all tiles here.
  return o ^ (((o >> 7) & 7) << 4);
}

__device__ __forceinline__ void gload_lds16(const void* g, void* l) {
  __builtin_amdgcn_global_load_lds(
      (const __attribute__((address_space(1))) unsigned*)g,
      (__attribute__((address_space(3))) unsigned*)l, 16, 0, 0);
}

__device__ __forceinline__ u16 f2bf(float f) {
  union { float f; unsigned u; } v;
  v.f = f;
  unsigned u = v.u;
  return (u16)((u + 0x7fffu + ((u >> 16) & 1u)) >> 16);
}

// ---------------- f32 -> bf16 cast (8 elem/thread) ----------------
__global__ __launch_bounds__(256) void cast_f32_bf16(const float* __restrict__ in,
                                                     u16* __restrict__ out, int n8) {
  int i = blockIdx.x * 256 + threadIdx.x;
  if (i >= n8) return;
  const float4* p = (const float4*)in + (size_t)i * 2;
  float4 a = p[0], b = p[1];
  u16x8 o;
  o[0] = f2bf(a.x); o[1] = f2bf(a.y); o[2] = f2bf(a.z); o[3] = f2bf(a.w);
  o[4] = f2bf(b.x); o[5] = f2bf(b.y); o[6] = f2bf(b.z); o[7] = f2bf(b.w);
  *((u16x8*)out + i) = o;
}

// ---------------- transpose+cast 1024x1024 f32 weights -> bf16 ----------------
__global__ __launch_bounds__(256) void transpose_w(const float* __restrict__ in,
                                                   u16* __restrict__ out) {
  __shared__ u16 t[64][65];
  int r0 = blockIdx.y * 64, c0 = blockIdx.x * 64;
  for (int i = threadIdx.x; i < 4096; i += 256) {
    int r = i >> 6, c = i & 63;
    t[r][c] = f2bf(in[(size_t)(r0 + r) * 1024 + c0 + c]);
  }
  __syncthreads();
  for (int i = threadIdx.x; i < 4096; i += 256) {
    int r = i >> 6, c = i & 63;
    out[(size_t)(c0 + r) * 1024 + r0 + c] = t[c][r];
  }
}

// ---------------- V[B,S,D](bf16) -> VT[b*H+h][64][S] ----------------
__global__ __launch_bounds__(256) void transpose_v(const u16* __restrict__ V,
                                                   u16* __restrict__ VT) {
  __shared__ u16 t[64][65];
  int s0 = blockIdx.x * 64;
  int bh = blockIdx.y, b = bh >> 4, h = bh & 15;
  const u16* src = V + (size_t)b * S_ * D_ + h * 64;
  u16* dst = VT + (size_t)bh * 64 * S_;
  for (int i = threadIdx.x; i < 4096; i += 256) {
    int s = i >> 6, dk = i & 63;
    t[s][dk] = src[(size_t)(s0 + s) * D_ + dk];
  }
  __syncthreads();
  for (int i = threadIdx.x; i < 4096; i += 256) {
    int dk = i >> 6, s = i & 63;
    dst[(size_t)dk * S_ + s0 + s] = t[s][dk];
  }
}

// ---------------- C[M,N] = A[M,K] * BT[N,K]^T (bf16 in), M=4096 N=1024 K=1024
// Tile 128x64, BK=64, 4 waves (2x2), each wave 64x32 (4x2 frags of 16x16).
// OUTF32: write float32 (final projection -> d_out), else bf16.
template <bool OUTF32>
__global__ __launch_bounds__(256) void gemm_bt(const u16* __restrict__ A,
                                               const u16* __restrict__ BT,
                                               void* __restrict__ Cv) {
  constexpr int K = 1024, N = 1024;
  __shared__ __align__(16) u16 lA[128 * 64];
  __shared__ __align__(16) u16 lB[64 * 64];
  const int tid = threadIdx.x, lane = tid & 63, w = tid >> 6;
  const int wr = w >> 1, wc = w & 1;
  const int m0 = blockIdx.x * 128, n0 = blockIdx.y * 64;
  const int g = lane >> 4, c16 = lane & 15;
  f32x4 acc[4][2] = {};
  const char* Ab = (const char*)(A + (size_t)m0 * K);
  const char* Bb = (const char*)(BT + (size_t)n0 * K);
  char* lAb = (char*)lA;
  char* lBb = (char*)lB;
  for (int kt = 0; kt < K; kt += 64) {
    // Dest LDS is linear; source address pre-swizzled (rule #21).
    for (int c = 0; c < 4; ++c) {
      unsigned o = w * 4096 + c * 1024 + lane * 16;
      unsigned u = swz(o);
      gload_lds16(Ab + (size_t)(u >> 7) * (K * 2) + kt * 2 + (u & 127),
                  lAb + w * 4096 + c * 1024);
    }
    for (int c = 0; c < 2; ++c) {
      unsigned o = w * 2048 + c * 1024 + lane * 16;
      unsigned u = swz(o);
      gload_lds16(Bb + (size_t)(u >> 7) * (K * 2) + kt * 2 + (u & 127),
                  lBb + w * 2048 + c * 1024);
    }
    asm volatile("s_waitcnt vmcnt(0)" ::: "memory");
    __syncthreads();
    for (int ks = 0; ks < 2; ++ks) {
      bf16x8 af[4], bf[2];
      for (int i = 0; i < 4; ++i) {
        unsigned row = wr * 64 + i * 16 + c16;
        unsigned o = row * 128 + ks * 64 + g * 16;
        af[i] = *(const bf16x8*)(lAb + (o ^ ((row & 7) << 4)));
      }
      for (int j = 0; j < 2; ++j) {
        unsigned row = wc * 32 + j * 16 + c16;
        unsigned o = row * 128 + ks * 64 + g * 16;
        bf[j] = *(const bf16x8*)(lBb + (o ^ ((row & 7) << 4)));
      }
      for (int i = 0; i < 4; ++i)
        for (int j = 0; j < 2; ++j)
          acc[i][j] = __builtin_amdgcn_mfma_f32_16x16x32_bf16(af[i], bf[j],
                                                              acc[i][j], 0, 0, 0);
    }
    __syncthreads();
  }
  // C/D layout: row=(lane>>4)*4+r, col=lane&15 (m89-verified)
  for (int i = 0; i < 4; ++i)
    for (int j = 0; j < 2; ++j) {
      int row = m0 + wr * 64 + i * 16 + g * 4;
      int col = n0 + wc * 32 + j * 16 + c16;
      for (int r = 0; r < 4; ++r) {
        if constexpr (OUTF32)
          ((float*)Cv)[(size_t)(row + r) * N + col] = acc[i][j][r];
        else
          ((u16*)Cv)[(size_t)(row + r) * N + col] = f2bf(acc[i][j][r]);
      }
    }
}

// ---------------- flash attention ----------------
// grid (S/64, B*H); 4 waves, wave w owns q rows [w*16, w*16+16).
__global__ __launch_bounds__(256) void flash_attn(const u16* __restrict__ Q,
                                                  const u16* __restrict__ K,
                                                  const u16* __restrict__ VT,
                                                  u16* __restrict__ O) {
  __shared__ __align__(16) u16 lQ[64 * 64];
  __shared__ __align__(16) u16 lK[64 * 64];
  __shared__ __align__(16) u16 lV[64 * 64];
  __shared__ __align__(16) u16 lP[64 * 64];
  const int tid = threadIdx.x, lane = tid & 63, w = tid >> 6;
  const int g = lane >> 4, c16 = lane & 15;
  const int q0 = blockIdx.x * 64;
  const int bh = blockIdx.y, b = bh >> 4, h = bh & 15;
  const char* Qb = (const char*)(Q + (size_t)(b * S_ + q0) * D_ + h * 64);
  const char* Kb = (const char*)(K + (size_t)b * S_ * D_ + h * 64);
  const char* Vb = (const char*)(VT + (size_t)bh * 64 * S_);
  char* lQb = (char*)lQ;
  char* lKb = (char*)lK;
  char* lVb = (char*)lV;
  char* lPb = (char*)lP;

  // stage Q tile once (64x64)
  for (int c = 0; c < 2; ++c) {
    unsigned o = w * 2048 + c * 1024 + lane * 16;
    unsigned u = swz(o);
    gload_lds16(Qb + (size_t)(u >> 7) * (D_ * 2) + (u & 127),
                lQb + w * 2048 + c * 1024);
  }
  float m_run[4], l_run[4];
  f32x4 oacc[4] = {};
  for (int r = 0; r < 4; ++r) { m_run[r] = -INFINITY; l_run[r] = 0.f; }
  asm volatile("s_waitcnt vmcnt(0)" ::: "memory");
  __syncthreads();
  bf16x8 qf[2];
  {
    unsigned row = w * 16 + c16;
    for (int ks = 0; ks < 2; ++ks) {
      unsigned o = row * 128 + ks * 64 + g * 16;
      qf[ks] = *(const bf16x8*)(lQb + (o ^ ((row & 7) << 4)));
    }
  }
  const float SC2 = 0.125f * 1.44269504088896340736f;  // SCALE * log2(e)
  for (int kv = 0; kv < S_; kv += 64) {
    for (int c = 0; c < 2; ++c) {
      unsigned o = w * 2048 + c * 1024 + lane * 16;
      unsigned u = swz(o);
      gload_lds16(Kb + (size_t)(kv + (u >> 7)) * (D_ * 2) + (u & 127),
                  lKb + w * 2048 + c * 1024);
      gload_lds16(Vb + (size_t)(u >> 7) * (S_ * 2) + (size_t)kv * 2 + (u & 127),
                  lVb + w * 2048 + c * 1024);
    }
    asm volatile("s_waitcnt vmcnt(0)" ::: "memory");
    __syncthreads();
    // S = Q K^T : K tile rows are kv (B^T layout), k = dk contiguous
    f32x4 s[4] = {};
    for (int ks = 0; ks < 2; ++ks) {
      for (int j = 0; j < 4; ++j) {
        unsigned row = j * 16 + c16;
        unsigned o = row * 128 + ks * 64 + g * 16;
        bf16x8 kf = *(const bf16x8*)(lKb + (o ^ ((row & 7) << 4)));
        s[j] = __builtin_amdgcn_mfma_f32_16x16x32_bf16(qf[ks], kf, s[j], 0, 0, 0);
      }
    }
    // online softmax; lane holds rows q=w*16+g*4+r, cols kv=j*16+c16
    for (int r = 0; r < 4; ++r) {
      float rm = fmaxf(fmaxf(s[0][r], s[1][r]), fmaxf(s[2][r], s[3][r]));
      rm = fmaxf(rm, __shfl_xor(rm, 1));
      rm = fmaxf(rm, __shfl_xor(rm, 2));
      rm = fmaxf(rm, __shfl_xor(rm, 4));
      rm = fmaxf(rm, __shfl_xor(rm, 8));
      float mn = fmaxf(m_run[r], rm);
      float sc = exp2f((m_run[r] - mn) * SC2);
      m_run[r] = mn;
      float p[4], rs = 0.f;
      for (int j = 0; j < 4; ++j) {
        p[j] = exp2f((s[j][r] - mn) * SC2);
        rs += p[j];
      }
      rs += __shfl_xor(rs, 1);
      rs += __shfl_xor(rs, 2);
      rs += __shfl_xor(rs, 4);
      rs += __shfl_xor(rs, 8);
      l_run[r] = l_run[r] * sc + rs;
      for (int j = 0; j < 4; ++j) oacc[j][r] *= sc;
      unsigned qrow = w * 16 + g * 4 + r;
      for (int j = 0; j < 4; ++j) {
        unsigned o = qrow * 128 + (unsigned)(j * 16 + c16) * 2;
        *(u16*)(lPb + (o ^ ((qrow & 7) << 4))) = f2bf(p[j]);
      }
    }
    __syncthreads();
    // O += P V : A-frag from lP (wave-private rows), B-frag from lV (=V^T tile)
    for (int ks = 0; ks < 2; ++ks) {
      unsigned prow = w * 16 + c16;
      unsigned po = prow * 128 + ks * 64 + g * 16;
      bf16x8 pf = *(const bf16x8*)(lPb + (po ^ ((prow & 7) << 4)));
      for (int j = 0; j < 4; ++j) {
        unsigned vrow = j * 16 + c16;
        unsigned vo = vrow * 128 + ks * 64 + g * 16;
        bf16x8 vf = *(const bf16x8*)(lVb + (vo ^ ((vrow & 7) << 4)));
        oacc[j] = __builtin_amdgcn_mfma_f32_16x16x32_bf16(pf, vf, oacc[j], 0, 0, 0);
      }
    }
    __syncthreads();
  }
  for (int j = 0; j < 4; ++j)
    for (int r = 0; r < 4; ++r) {
      int q = q0 + w * 16 + g * 4 + r;
      int col = h * 64 + j * 16 + c16;
      O[(size_t)(b * S_ + q) * D_ + col] = f2bf(oacc[j][r] / l_run[r]);
    }
}

extern "C" void kernel_launch(void* const* d_in, const int* in_sizes, int n_in,
                              void* d_out, int out_size, void* d_ws, size_t ws_size,
                              hipStream_t stream) {
  const float* q_in = (const float*)d_in[0];
  const float* k_in = (const float*)d_in[1];
  const float* v_in = (const float*)d_in[2];
  const float* Wq = (const float*)d_in[3];
  const float* Wk = (const float*)d_in[4];
  const float* Wv = (const float*)d_in[5];
  const float* Wo = (const float*)d_in[6];
  u16* ws = (u16*)d_ws;
  const size_t WSZ = (size_t)1024 * 1024;
  const size_t TSZ = (size_t)B_ * S_ * D_;  // 4,194,304
  u16* WqT = ws;
  u16* WkT = ws + WSZ;
  u16* WvT = ws + 2 * WSZ;
  u16* WoT = ws + 3 * WSZ;
  u16* Qc = ws + 4 * WSZ;   // casted bf16 inputs
  u16* Kc = Qc + TSZ;
  u16* Vc = Kc + TSZ;
  u16* Qb = Vc + TSZ;       // projected
  u16* Kb = Qb + TSZ;
  u16* Vb = Kb + TSZ;
  u16* VTb = Kc;            // alias: Kc dead after K projection
  u16* Ob = Qc;             // alias: Qc dead after Q projection
  dim3 tb(256);
  transpose_w<<<dim3(16, 16), tb, 0, stream>>>(Wq, WqT);
  transpose_w<<<dim3(16, 16), tb, 0, stream>>>(Wk, WkT);
  transpose_w<<<dim3(16, 16), tb, 0, stream>>>(Wv, WvT);
  transpose_w<<<dim3(16, 16), tb, 0, stream>>>(Wo, WoT);
  int n8 = (int)(TSZ / 8);
  cast_f32_bf16<<<dim3(n8 / 256), tb, 0, stream>>>(q_in, Qc, n8);
  cast_f32_bf16<<<dim3(n8 / 256), tb, 0, stream>>>(k_in, Kc, n8);
  cast_f32_bf16<<<dim3(n8 / 256), tb, 0, stream>>>(v_in, Vc, n8);
  gemm_bt<false><<<dim3(32, 16), tb, 0, stream>>>(Qc, WqT, Qb);
  gemm_bt<false><<<dim3(32, 16), tb, 0, stream>>>(Kc, WkT, Kb);
  gemm_bt<false><<<dim3(32, 16), tb, 0, stream>>>(Vc, WvT, Vb);
  transpose_v<<<dim3(32, 32), tb, 0, stream>>>(Vb, VTb);
  flash_attn<<<dim3(32, 32), tb, 0, stream>>>(Qb, Kb, VTb, Ob);
  gemm_bt<true><<<dim3(32, 16), tb, 0, stream>>>(Ob, WoT, d_out);  // f32 out!
}